// Round 1
// baseline (432.701 us; speedup 1.0000x reference)
//
#include <hip/hip_runtime.h>

// ---------------------------------------------------------------------------
// AttentionMultiHead: x[8,1024,1024] f32, per-head Wq/Wk/Wv[16,1024,64]+bias,
// Wo[1024,64]+bo. Outputs: z_out[8,1024,64] f32, att[8,16,1024,1024] f32 (raw).
// Pipeline:
//   1. pack_x:    x -> bf16 [8192][1024]
//   2. pack_w:    Wq|Wk|Wv -> bf16 B^T layout Wp[3072][1024]
//      pack_misc: Wo -> bf16 B^T Wop[64][1024]; biases -> bqkv[3072] f32
//   3. gemm_qkv:  128x128 tile MFMA GEMM, bias+relu epilogue -> q,k,v bf16 [bh][s][64]
//   4. transpose_v: v -> vT bf16 [bh][64][1024]
//   5. attn:      flash-style per (b,h,qtile=64): QK^T -> att (f32, raw) +
//                 online softmax (scale 1/8) + PV -> heads bf16 [b][s][h*64+dk]
//   6. gemm_out:  z_out = relu(heads @ Wo + bo) -> d_out[0:524288]
// ---------------------------------------------------------------------------

typedef __bf16 bf16x8 __attribute__((ext_vector_type(8)));
typedef float f32x4 __attribute__((ext_vector_type(4)));
typedef unsigned short u16x8 __attribute__((ext_vector_type(8)));
typedef unsigned short u16x4 __attribute__((ext_vector_type(4)));

typedef __attribute__((address_space(1))) unsigned int as1_u32;
typedef __attribute__((address_space(3))) unsigned int as3_u32;

#define MFMA16(a, b, c) __builtin_amdgcn_mfma_f32_16x16x32_bf16(a, b, c, 0, 0, 0)

__device__ __forceinline__ void gload_lds16(const void* g, void* l) {
  __builtin_amdgcn_global_load_lds((const as1_u32*)g, (as3_u32*)l, 16, 0, 0);
}

__device__ __forceinline__ unsigned short f2bf(float f) {
  union { float f; unsigned u; } a; a.f = f;
  unsigned r = a.u + 0x7FFFu + ((a.u >> 16) & 1u);  // RNE
  return (unsigned short)(r >> 16);
}

// ---------------- pack kernels ----------------
__global__ __launch_bounds__(256) void pack_x(const float* __restrict__ x, ushort* __restrict__ xb) {
  const size_t i = ((size_t)blockIdx.x * 256 + threadIdx.x) * 4;
  const float4 v = *(const float4*)(x + i);
  u16x4 o; o[0] = f2bf(v.x); o[1] = f2bf(v.y); o[2] = f2bf(v.z); o[3] = f2bf(v.w);
  *(u16x4*)(xb + i) = o;
}

// Wp[n][d], n = proj*1024 + h*64 + k  (B^T layout: row n contiguous over d)
__global__ __launch_bounds__(256) void pack_w(const float* __restrict__ Wq, const float* __restrict__ Wk,
                                              const float* __restrict__ Wv, ushort* __restrict__ Wp) {
  const int o = blockIdx.x * 256 + threadIdx.x;  // 0 .. 3072*1024
  const int n = o >> 10, d = o & 1023;
  const int proj = n >> 10, hk = n & 1023;
  const float* W = proj == 0 ? Wq : (proj == 1 ? Wk : Wv);
  const int h = hk >> 6, kk = hk & 63;
  Wp[o] = f2bf(W[((size_t)h * 1024 + d) * 64 + kk]);
}

__global__ __launch_bounds__(256) void pack_misc(const float* __restrict__ Wo, const float* __restrict__ bq,
                                                 const float* __restrict__ bk, const float* __restrict__ bv,
                                                 ushort* __restrict__ Wop, float* __restrict__ bqkv) {
  const int idx = blockIdx.x * 256 + threadIdx.x;
  if (idx < 65536) {
    const int n = idx >> 10, c = idx & 1023;   // Wop[n][c] = Wo[c][n]
    Wop[idx] = f2bf(Wo[c * 64 + n]);
  } else if (idx < 65536 + 3072) {
    const int n = idx - 65536;
    const int proj = n >> 10;
    const float* bb = proj == 0 ? bq : (proj == 1 ? bk : bv);
    bqkv[n] = bb[n & 1023];
  }
}

// ---------------- QKV projection GEMM ----------------
// C[8192][3072] = relu(xb @ Wp^T + bqkv), scattered to q/k/v bf16 [bh][s][64].
// 128x128 tile, BK=32, 4 waves in 2x2, each wave 64x64 (4x4 of 16x16x32 MFMA).
__global__ __launch_bounds__(256) void gemm_qkv(const ushort* __restrict__ xb, const ushort* __restrict__ Wp,
                                                const float* __restrict__ bqkv, ushort* __restrict__ qo,
                                                ushort* __restrict__ ko, ushort* __restrict__ vo) {
  __shared__ ushort As[128 * 32], Bs[128 * 32];
  const int t = threadIdx.x, w = t >> 6, l = t & 63, lg = l >> 4, lr = l & 15;
  const int m0 = blockIdx.y * 128, n0 = blockIdx.x * 128;
  const int wm = w >> 1, wn = w & 1;
  const int srow = l >> 2, sslot = l & 3;
  f32x4 acc[4][4] = {};
  for (int kt = 0; kt < 32; ++kt) {
    __syncthreads();
#pragma unroll
    for (int c = 0; c < 2; ++c) {
      const int cc = w * 2 + c;              // 0..7, 1KB chunk per wave-call
      const int row = cc * 16 + srow;        // LDS linear == row*64B + slot*16B
      gload_lds16(xb + (size_t)(m0 + row) * 1024 + kt * 32 + sslot * 8, &As[cc * 512]);
      gload_lds16(Wp + (size_t)(n0 + row) * 1024 + kt * 32 + sslot * 8, &Bs[cc * 512]);
    }
    __syncthreads();
    bf16x8 af[4], bfr[4];
#pragma unroll
    for (int mt = 0; mt < 4; ++mt)
      af[mt] = *(const bf16x8*)(&As[(wm * 64 + mt * 16 + lr) * 32 + lg * 8]);
#pragma unroll
    for (int nt = 0; nt < 4; ++nt)
      bfr[nt] = *(const bf16x8*)(&Bs[(wn * 64 + nt * 16 + lr) * 32 + lg * 8]);
#pragma unroll
    for (int mt = 0; mt < 4; ++mt)
#pragma unroll
      for (int nt = 0; nt < 4; ++nt)
        acc[mt][nt] = MFMA16(af[mt], bfr[nt], acc[mt][nt]);
  }
  // epilogue: bias + relu -> bf16 scatter into q/k/v [b*16+h][s][dk]
#pragma unroll
  for (int nt = 0; nt < 4; ++nt) {
    const int n = n0 + wn * 64 + nt * 16 + lr;
    const float bias = bqkv[n];
    const int proj = n >> 10, h = (n >> 6) & 15, dk = n & 63;
    ushort* op = proj == 0 ? qo : (proj == 1 ? ko : vo);
#pragma unroll
    for (int mt = 0; mt < 4; ++mt)
#pragma unroll
      for (int j = 0; j < 4; ++j) {
        const int m = m0 + wm * 64 + mt * 16 + lg * 4 + j;
        const int b = m >> 10, s = m & 1023;
        float vv = acc[mt][nt][j] + bias;
        vv = vv > 0.f ? vv : 0.f;
        op[((size_t)(b * 16 + h) * 1024 + s) * 64 + dk] = f2bf(vv);
      }
  }
}

// ---------------- v transpose: [bh][s][64] -> vT [bh][64][1024] ----------------
__global__ __launch_bounds__(256) void transpose_v(const ushort* __restrict__ v, ushort* __restrict__ vT) {
  __shared__ ushort tile[64][72];
  const int bh = blockIdx.y, st = blockIdx.x;
  const int t = threadIdx.x;
  const ushort* vb = v + ((size_t)bh * 1024 + st * 64) * 64;
  const int r = t >> 2, cb = (t & 3) * 16;
  u16x8 a0 = *(const u16x8*)(vb + r * 64 + cb);
  u16x8 a1 = *(const u16x8*)(vb + r * 64 + cb + 8);
  *(u16x8*)(&tile[r][cb]) = a0;
  *(u16x8*)(&tile[r][cb + 8]) = a1;
  __syncthreads();
  const int d = t >> 2, sb = (t & 3) * 16;
#pragma unroll
  for (int i = 0; i < 2; ++i) {
    u16x8 o;
#pragma unroll
    for (int jj = 0; jj < 8; ++jj) o[jj] = tile[sb + i * 8 + jj][d];
    *(u16x8*)(vT + ((size_t)bh * 64 + d) * 1024 + st * 64 + sb + i * 8) = o;
  }
}

// ---------------- fused attention ----------------
// block = (qtile, bh); 4 waves x 16 q-rows. KV tiles of 64. Writes raw scores
// to att (f32), online softmax (scale 0.125), PV via LDS p round-trip, heads bf16.
__global__ __launch_bounds__(256) void attn_kernel(const ushort* __restrict__ qg, const ushort* __restrict__ kg,
                                                   const ushort* __restrict__ vT, float* __restrict__ att,
                                                   ushort* __restrict__ heads) {
  const int qt = blockIdx.x, bh = blockIdx.y;
  const int t = threadIdx.x, w = t >> 6, l = t & 63;
  const int lg = l >> 4, lr = l & 15;
  __shared__ ushort p_lds[2][4][16][72];  // [parity][wave][qrow][kv+pad]

  const ushort* qb = qg + (size_t)bh * 1024 * 64;
  const ushort* kb = kg + (size_t)bh * 1024 * 64;
  const ushort* vb = vT + (size_t)bh * 64 * 1024;
  const int qrow0 = qt * 64 + w * 16;

  const bf16x8 qf0 = *(const bf16x8*)(qb + (qrow0 + lr) * 64 + lg * 8);
  const bf16x8 qf1 = *(const bf16x8*)(qb + (qrow0 + lr) * 64 + 32 + lg * 8);

  f32x4 oacc[4] = {};
  float mrun[4] = {-1e30f, -1e30f, -1e30f, -1e30f};
  float lrun[4] = {0.f, 0.f, 0.f, 0.f};
  float* attw = att + ((size_t)bh * 1024 + qrow0) * 1024;

  for (int kt = 0; kt < 16; ++kt) {
    const int kv0 = kt * 64;
    f32x4 sf[4] = {};
#pragma unroll
    for (int nt = 0; nt < 4; ++nt) {
      const ushort* kr = kb + (kv0 + nt * 16 + lr) * 64 + lg * 8;
      bf16x8 kf0 = *(const bf16x8*)(kr);
      bf16x8 kf1 = *(const bf16x8*)(kr + 32);
      sf[nt] = MFMA16(qf0, kf0, sf[nt]);
      sf[nt] = MFMA16(qf1, kf1, sf[nt]);
    }
    // raw (unscaled) attention scores out. C-layout: row=lg*4+j, col=nt*16+lr.
#pragma unroll
    for (int nt = 0; nt < 4; ++nt)
#pragma unroll
      for (int j = 0; j < 4; ++j)
        attw[(size_t)(lg * 4 + j) * 1024 + kv0 + nt * 16 + lr] = sf[nt][j];
    // online softmax (scaled domain: s*0.125)
    float tm[4];
#pragma unroll
    for (int j = 0; j < 4; ++j)
      tm[j] = fmaxf(fmaxf(sf[0][j], sf[1][j]), fmaxf(sf[2][j], sf[3][j])) * 0.125f;
#pragma unroll
    for (int j = 0; j < 4; ++j)
#pragma unroll
      for (int off = 1; off < 16; off <<= 1)
        tm[j] = fmaxf(tm[j], __shfl_xor(tm[j], off, 16));
    float fac[4], psum[4];
#pragma unroll
    for (int j = 0; j < 4; ++j) {
      const float mn = fmaxf(mrun[j], tm[j]);
      fac[j] = __expf(mrun[j] - mn);
      mrun[j] = mn;
      psum[j] = 0.f;
    }
#pragma unroll
    for (int nt = 0; nt < 4; ++nt)
#pragma unroll
      for (int j = 0; j < 4; ++j) {
        const float p = __expf(sf[nt][j] * 0.125f - mrun[j]);
        psum[j] += p;
        p_lds[kt & 1][w][lg * 4 + j][nt * 16 + lr] = f2bf(p);
      }
#pragma unroll
    for (int j = 0; j < 4; ++j) {
#pragma unroll
      for (int off = 1; off < 16; off <<= 1)
        psum[j] += __shfl_xor(psum[j], off, 16);
      lrun[j] = lrun[j] * fac[j] + psum[j];
    }
#pragma unroll
    for (int nt = 0; nt < 4; ++nt)
#pragma unroll
      for (int j = 0; j < 4; ++j) oacc[nt][j] *= fac[j];
    // per-wave LDS region; DS ops execute in wave program order, waitcnt for RAW
    asm volatile("s_waitcnt lgkmcnt(0)" ::: "memory");
    __builtin_amdgcn_sched_barrier(0);
    const bf16x8 pa0 = *(const bf16x8*)(&p_lds[kt & 1][w][lr][lg * 8]);
    const bf16x8 pa1 = *(const bf16x8*)(&p_lds[kt & 1][w][lr][32 + lg * 8]);
#pragma unroll
    for (int nt = 0; nt < 4; ++nt) {
      const ushort* vr = vb + (nt * 16 + lr) * 1024 + kv0 + lg * 8;
      bf16x8 vf0 = *(const bf16x8*)(vr);
      bf16x8 vf1 = *(const bf16x8*)(vr + 32);
      oacc[nt] = MFMA16(pa0, vf0, oacc[nt]);
      oacc[nt] = MFMA16(pa1, vf1, oacc[nt]);
    }
  }
  const int b = bh >> 4, h = bh & 15;
#pragma unroll
  for (int nt = 0; nt < 4; ++nt)
#pragma unroll
    for (int j = 0; j < 4; ++j) {
      const float o = oacc[nt][j] / lrun[j];
      heads[(size_t)(b * 1024 + qrow0 + lg * 4 + j) * 1024 + h * 64 + nt * 16 + lr] = f2bf(o);
    }
}

// ---------------- output GEMM: z_out = relu(heads @ Wo + bo) ----------------
__global__ __launch_bounds__(256) void gemm_out(const ushort* __restrict__ z, const ushort* __restrict__ Wop,
                                                const float* __restrict__ bo, float* __restrict__ out) {
  const int t = threadIdx.x, w = t >> 6, l = t & 63, lg = l >> 4, lr = l & 15;
  const int m0 = blockIdx.x * 64 + w * 16;
  f32x4 acc[4] = {};
  for (int kk = 0; kk < 32; ++kk) {
    bf16x8 af = *(const bf16x8*)(z + (size_t)(m0 + lr) * 1024 + kk * 32 + lg * 8);
#pragma unroll
    for (int nt = 0; nt < 4; ++nt) {
      bf16x8 bfr = *(const bf16x8*)(Wop + (size_t)(nt * 16 + lr) * 1024 + kk * 32 + lg * 8);
      acc[nt] = MFMA16(af, bfr, acc[nt]);
    }
  }
#pragma unroll
  for (int nt = 0; nt < 4; ++nt) {
    const int n = nt * 16 + lr;
    const float bb = bo[n];
#pragma unroll
    for (int j = 0; j < 4; ++j) {
      const int m = m0 + lg * 4 + j;
      float vv = acc[nt][j] + bb;
      out[(size_t)m * 64 + n] = vv > 0.f ? vv : 0.f;
    }
  }
}

// ---------------------------------------------------------------------------
extern "C" void kernel_launch(void* const* d_in, const int* in_sizes, int n_in,
                              void* d_out, int out_size, void* d_ws, size_t ws_size,
                              hipStream_t stream) {
  const float* x  = (const float*)d_in[0];
  const float* Wq = (const float*)d_in[1];
  const float* bq = (const float*)d_in[2];
  const float* Wk = (const float*)d_in[3];
  const float* bk = (const float*)d_in[4];
  const float* Wv = (const float*)d_in[5];
  const float* bv = (const float*)d_in[6];
  const float* Wo = (const float*)d_in[7];
  const float* bo = (const float*)d_in[8];
  float* out = (float*)d_out;            // z_out: 8*1024*64 = 524288 f32
  float* att = out + 524288;             // att:   8*16*1024*1024 f32

  // workspace layout (needs ~108 MB)
  char* ws = (char*)d_ws;
  size_t off = 0;
  ushort* xb  = (ushort*)(ws + off); off += (size_t)8192 * 1024 * 2;
  ushort* Wp  = (ushort*)(ws + off); off += (size_t)3072 * 1024 * 2;
  ushort* Wop = (ushort*)(ws + off); off += (size_t)64 * 1024 * 2;
  float* bqkv = (float*)(ws + off);  off += (size_t)3072 * 4;
  ushort* q   = (ushort*)(ws + off); off += (size_t)128 * 1024 * 64 * 2;
  ushort* k   = (ushort*)(ws + off); off += (size_t)128 * 1024 * 64 * 2;
  ushort* v   = (ushort*)(ws + off); off += (size_t)128 * 1024 * 64 * 2;
  ushort* vT  = (ushort*)(ws + off); off += (size_t)128 * 64 * 1024 * 2;
  ushort* hds = (ushort*)(ws + off); off += (size_t)8192 * 1024 * 2;
  (void)ws_size; (void)in_sizes; (void)n_in; (void)out_size;

  pack_x<<<dim3(8192), dim3(256), 0, stream>>>(x, xb);
  pack_w<<<dim3(12288), dim3(256), 0, stream>>>(Wq, Wk, Wv, Wp);
  pack_misc<<<dim3(269), dim3(256), 0, stream>>>(Wo, bq, bk, bv, Wop, bqkv);
  gemm_qkv<<<dim3(24, 64), dim3(256), 0, stream>>>(xb, Wp, bqkv, q, k, v);
  transpose_v<<<dim3(16, 128), dim3(256), 0, stream>>>(v, vT);
  attn_kernel<<<dim3(16, 128), dim3(256), 0, stream>>>(q, k, vT, att, hds);
  gemm_out<<<dim3(128), dim3(256), 0, stream>>>(hds, Wop, bo, out);
}

// Round 3
// 407.559 us; speedup vs baseline: 1.0617x; 1.0617x over previous
//
#include <hip/hip_runtime.h>

// ---------------------------------------------------------------------------
// AttentionMultiHead: x[8,1024,1024] f32, per-head Wq/Wk/Wv[16,1024,64]+bias,
// Wo[1024,64]+bo. Outputs: z_out[8,1024,64] f32, att[8,16,1024,1024] f32 (raw).
// Pipeline:
//   1. pack_x:    x -> bf16 [8192][1024]
//   2. pack_w:    Wq|Wk|Wv -> bf16 B^T layout Wp[3072][1024]  (XCD-swizzled)
//      pack_misc: Wo -> bf16 B^T Wop[64][1024]; biases -> bqkv[3072] f32
//   3. gemm_qkv:  128x128 tile MFMA GEMM, bias+relu epilogue -> q,k bf16
//                 [bh][s][64]; v written TRANSPOSED -> vT [bh][64][1024]
//   4. attn:      flash-style per (b,h,qtile=64): QK^T -> att (f32, raw) +
//                 online softmax (exp2 domain) + PV (V prefetched before the
//                 softmax VALU block) -> heads bf16 [b][s][h*64+dk]
//   5. gemm_out:  z_out = relu(heads @ Wo + bo), 2-way K-split + LDS reduce
// ---------------------------------------------------------------------------

typedef __bf16 bf16x8 __attribute__((ext_vector_type(8)));
typedef float f32x4 __attribute__((ext_vector_type(4)));
typedef unsigned short u16x8 __attribute__((ext_vector_type(8)));
typedef unsigned short u16x4 __attribute__((ext_vector_type(4)));

typedef __attribute__((address_space(1))) unsigned int as1_u32;
typedef __attribute__((address_space(3))) unsigned int as3_u32;

#define MFMA16(a, b, c) __builtin_amdgcn_mfma_f32_16x16x32_bf16(a, b, c, 0, 0, 0)

__device__ __forceinline__ void gload_lds16(const void* g, void* l) {
  __builtin_amdgcn_global_load_lds((const as1_u32*)g, (as3_u32*)l, 16, 0, 0);
}

__device__ __forceinline__ unsigned short f2bf(float f) {
  union { float f; unsigned u; } a; a.f = f;
  unsigned r = a.u + 0x7FFFu + ((a.u >> 16) & 1u);  // RNE
  return (unsigned short)(r >> 16);
}

// ---------------- pack kernels ----------------
__global__ __launch_bounds__(256) void pack_x(const float* __restrict__ x, ushort* __restrict__ xb) {
  const size_t i = ((size_t)blockIdx.x * 256 + threadIdx.x) * 4;
  const float4 v = *(const float4*)(x + i);
  u16x4 o; o[0] = f2bf(v.x); o[1] = f2bf(v.y); o[2] = f2bf(v.z); o[3] = f2bf(v.w);
  *(u16x4*)(xb + i) = o;
}

// Wp[n][d], n = proj*1024 + h*64 + k  (B^T layout). XCD swizzle: 12288 blocks,
// chunk 1536/XCD so strided W reads stay in one XCD's L2.
__global__ __launch_bounds__(256) void pack_w(const float* __restrict__ Wq, const float* __restrict__ Wk,
                                              const float* __restrict__ Wv, ushort* __restrict__ Wp) {
  const int bid = blockIdx.x;
  const int swz = (bid & 7) * 1536 + (bid >> 3);
  const int o = swz * 256 + threadIdx.x;  // 0 .. 3072*1024
  const int n = o >> 10, d = o & 1023;
  const int proj = n >> 10, hk = n & 1023;
  const float* W = proj == 0 ? Wq : (proj == 1 ? Wk : Wv);
  const int h = hk >> 6, kk = hk & 63;
  Wp[o] = f2bf(W[((size_t)h * 1024 + d) * 64 + kk]);
}

__global__ __launch_bounds__(256) void pack_misc(const float* __restrict__ Wo, const float* __restrict__ bq,
                                                 const float* __restrict__ bk, const float* __restrict__ bv,
                                                 ushort* __restrict__ Wop, float* __restrict__ bqkv) {
  const int idx = blockIdx.x * 256 + threadIdx.x;
  if (idx < 65536) {
    const int n = idx >> 10, c = idx & 1023;   // Wop[n][c] = Wo[c][n]
    Wop[idx] = f2bf(Wo[c * 64 + n]);
  } else if (idx < 65536 + 3072) {
    const int n = idx - 65536;
    const int proj = n >> 10;
    const float* bb = proj == 0 ? bq : (proj == 1 ? bk : bv);
    bqkv[n] = bb[n & 1023];
  }
}

// ---------------- QKV projection GEMM ----------------
// C[8192][3072] = relu(xb @ Wp^T + bqkv). q,k scattered bf16 [bh][s][64];
// v written transposed -> vT[bh][64][1024] (kills the transpose kernel).
// 128x128 tile, BK=32, 4 waves 2x2, each wave 64x64 (4x4 of 16x16x32 MFMA).
__global__ __launch_bounds__(256) void gemm_qkv(const ushort* __restrict__ xb, const ushort* __restrict__ Wp,
                                                const float* __restrict__ bqkv, ushort* __restrict__ qo,
                                                ushort* __restrict__ ko, ushort* __restrict__ vTo) {
  __shared__ ushort As[128 * 32], Bs[128 * 32];
  const int bid = blockIdx.x;                 // 1536 blocks
  const int swz = (bid & 7) * 192 + (bid >> 3);
  const int by = swz / 24, bx = swz - by * 24;
  const int t = threadIdx.x, w = t >> 6, l = t & 63, lg = l >> 4, lr = l & 15;
  const int m0 = by * 128, n0 = bx * 128;
  const int wm = w >> 1, wn = w & 1;
  const int srow = l >> 2, sslot = l & 3;
  f32x4 acc[4][4] = {};
  for (int kt = 0; kt < 32; ++kt) {
    __syncthreads();
#pragma unroll
    for (int c = 0; c < 2; ++c) {
      const int cc = w * 2 + c;              // 0..7, 1KB chunk per wave-call
      const int row = cc * 16 + srow;        // LDS linear == row*64B + slot*16B
      gload_lds16(xb + (size_t)(m0 + row) * 1024 + kt * 32 + sslot * 8, &As[cc * 512]);
      gload_lds16(Wp + (size_t)(n0 + row) * 1024 + kt * 32 + sslot * 8, &Bs[cc * 512]);
    }
    __syncthreads();
    bf16x8 af[4], bfr[4];
#pragma unroll
    for (int mt = 0; mt < 4; ++mt)
      af[mt] = *(const bf16x8*)(&As[(wm * 64 + mt * 16 + lr) * 32 + lg * 8]);
#pragma unroll
    for (int nt = 0; nt < 4; ++nt)
      bfr[nt] = *(const bf16x8*)(&Bs[(wn * 64 + nt * 16 + lr) * 32 + lg * 8]);
#pragma unroll
    for (int mt = 0; mt < 4; ++mt)
#pragma unroll
      for (int nt = 0; nt < 4; ++nt)
        acc[mt][nt] = MFMA16(af[mt], bfr[nt], acc[mt][nt]);
  }
  // epilogue: bias + relu -> bf16. proj uniform across the wave (16-aligned n-chunks).
#pragma unroll
  for (int nt = 0; nt < 4; ++nt) {
    const int n = n0 + wn * 64 + nt * 16 + lr;
    const float bias = bqkv[n];
    const int proj = n >> 10, h = (n >> 6) & 15, dk = n & 63;
#pragma unroll
    for (int mt = 0; mt < 4; ++mt) {
      const int mb = m0 + wm * 64 + mt * 16 + lg * 4;  // j-quad base, same b & 4-aligned s
      const int b = mb >> 10, s = mb & 1023;
      float vv[4];
#pragma unroll
      for (int j = 0; j < 4; ++j) {
        float a = acc[mt][nt][j] + bias;
        vv[j] = a > 0.f ? a : 0.f;
      }
      if (proj == 2) {
        u16x4 o; o[0] = f2bf(vv[0]); o[1] = f2bf(vv[1]); o[2] = f2bf(vv[2]); o[3] = f2bf(vv[3]);
        *(u16x4*)(vTo + ((size_t)(b * 16 + h) * 64 + dk) * 1024 + s) = o;
      } else {
        ushort* op = proj == 0 ? qo : ko;
#pragma unroll
        for (int j = 0; j < 4; ++j)
          op[((size_t)(b * 16 + h) * 1024 + s + j) * 64 + dk] = f2bf(vv[j]);
      }
    }
  }
}

// ---------------- fused attention ----------------
// 2048 blocks (XCD-swizzled so all 16 q-tiles of a bh share one XCD's L2);
// 4 waves x 16 q-rows. KV tiles of 64. Raw scores -> att f32; softmax in exp2
// domain; V frags prefetched before the softmax VALU block; PV via LDS P
// round-trip (cross-lane transpose); heads bf16.
__global__ __launch_bounds__(256) void attn_kernel(const ushort* __restrict__ qg, const ushort* __restrict__ kg,
                                                   const ushort* __restrict__ vT, float* __restrict__ att,
                                                   ushort* __restrict__ heads) {
  const int bid = blockIdx.x;                 // 2048
  const int swz = (bid & 7) * 256 + (bid >> 3);
  const int qt = swz & 15, bh = swz >> 4;
  const int t = threadIdx.x, w = t >> 6, l = t & 63;
  const int lg = l >> 4, lr = l & 15;
  __shared__ ushort p_lds[2][4][16][72];  // [parity][wave][qrow][kv+pad]

  const ushort* qb = qg + (size_t)bh * 1024 * 64;
  const ushort* kb = kg + (size_t)bh * 1024 * 64;
  const ushort* vb = vT + (size_t)bh * 64 * 1024;
  const int qrow0 = qt * 64 + w * 16;

  const bf16x8 qf0 = *(const bf16x8*)(qb + (qrow0 + lr) * 64 + lg * 8);
  const bf16x8 qf1 = *(const bf16x8*)(qb + (qrow0 + lr) * 64 + 32 + lg * 8);

  const float C2 = 0.125f * 1.44269504f;  // scale into exp2 domain
  f32x4 oacc[4] = {};
  float mrun[4] = {-1e30f, -1e30f, -1e30f, -1e30f};
  float lrun[4] = {0.f, 0.f, 0.f, 0.f};
  float* attw = att + ((size_t)bh * 1024 + qrow0) * 1024;

  for (int kt = 0; kt < 16; ++kt) {
    const int kv0 = kt * 64;
    f32x4 sf[4] = {};
#pragma unroll
    for (int nt = 0; nt < 4; ++nt) {
      const ushort* kr = kb + (kv0 + nt * 16 + lr) * 64 + lg * 8;
      bf16x8 kf0 = *(const bf16x8*)(kr);
      bf16x8 kf1 = *(const bf16x8*)(kr + 32);
      sf[nt] = MFMA16(qf0, kf0, sf[nt]);
      sf[nt] = MFMA16(qf1, kf1, sf[nt]);
    }
    // prefetch V fragments NOW so their latency hides under store+softmax VALU
    bf16x8 vf[4][2];
#pragma unroll
    for (int nt = 0; nt < 4; ++nt) {
      const ushort* vr = vb + (nt * 16 + lr) * 1024 + kv0 + lg * 8;
      vf[nt][0] = *(const bf16x8*)(vr);
      vf[nt][1] = *(const bf16x8*)(vr + 32);
    }
    // raw (unscaled) attention scores out. C-layout: row=lg*4+j, col=nt*16+lr.
#pragma unroll
    for (int nt = 0; nt < 4; ++nt)
#pragma unroll
      for (int j = 0; j < 4; ++j)
        attw[(size_t)(lg * 4 + j) * 1024 + kv0 + nt * 16 + lr] = sf[nt][j];
    // online softmax in exp2 domain
    float tm[4];
#pragma unroll
    for (int j = 0; j < 4; ++j)
      tm[j] = fmaxf(fmaxf(sf[0][j], sf[1][j]), fmaxf(sf[2][j], sf[3][j])) * C2;
#pragma unroll
    for (int j = 0; j < 4; ++j)
#pragma unroll
      for (int off = 1; off < 16; off <<= 1)
        tm[j] = fmaxf(tm[j], __shfl_xor(tm[j], off, 16));
    float fac[4], psum[4];
#pragma unroll
    for (int j = 0; j < 4; ++j) {
      const float mn = fmaxf(mrun[j], tm[j]);
      fac[j] = exp2f(mrun[j] - mn);
      mrun[j] = mn;
      psum[j] = 0.f;
    }
#pragma unroll
    for (int nt = 0; nt < 4; ++nt)
#pragma unroll
      for (int j = 0; j < 4; ++j) {
        const float p = exp2f(__builtin_fmaf(sf[nt][j], C2, -mrun[j]));
        psum[j] += p;
        p_lds[kt & 1][w][lg * 4 + j][nt * 16 + lr] = f2bf(p);
      }
#pragma unroll
    for (int j = 0; j < 4; ++j) {
#pragma unroll
      for (int off = 1; off < 16; off <<= 1)
        psum[j] += __shfl_xor(psum[j], off, 16);
      lrun[j] = lrun[j] * fac[j] + psum[j];
    }
#pragma unroll
    for (int nt = 0; nt < 4; ++nt)
#pragma unroll
      for (int j = 0; j < 4; ++j) oacc[nt][j] *= fac[j];
    // per-wave LDS region; DS ops execute in wave program order, waitcnt for RAW
    asm volatile("s_waitcnt lgkmcnt(0)" ::: "memory");
    __builtin_amdgcn_sched_barrier(0);
    const bf16x8 pa0 = *(const bf16x8*)(&p_lds[kt & 1][w][lr][lg * 8]);
    const bf16x8 pa1 = *(const bf16x8*)(&p_lds[kt & 1][w][lr][32 + lg * 8]);
#pragma unroll
    for (int nt = 0; nt < 4; ++nt) {
      oacc[nt] = MFMA16(pa0, vf[nt][0], oacc[nt]);
      oacc[nt] = MFMA16(pa1, vf[nt][1], oacc[nt]);
    }
  }
  const int b = bh >> 4, h = bh & 15;
#pragma unroll
  for (int nt = 0; nt < 4; ++nt)
#pragma unroll
    for (int j = 0; j < 4; ++j) {
      const float o = oacc[nt][j] / lrun[j];
      heads[(size_t)(b * 1024 + qrow0 + lg * 4 + j) * 1024 + h * 64 + nt * 16 + lr] = f2bf(o);
    }
}

// ---------------- output GEMM: z_out = relu(heads @ Wo + bo) ----------------
// 256 blocks; 4 waves = 2 m-halves x 2 k-halves; LDS reduce of the k-split.
__global__ __launch_bounds__(256) void gemm_out(const ushort* __restrict__ z, const ushort* __restrict__ Wop,
                                                const float* __restrict__ bo, float* __restrict__ out) {
  __shared__ float red[2][16][64];
  const int t = threadIdx.x, w = t >> 6, l = t & 63, lg = l >> 4, lr = l & 15;
  const int wm = w & 1, kh = w >> 1;
  const int m0 = blockIdx.x * 32 + wm * 16;
  f32x4 acc[4] = {};
  for (int kk = kh * 16; kk < kh * 16 + 16; ++kk) {
    bf16x8 af = *(const bf16x8*)(z + (size_t)(m0 + lr) * 1024 + kk * 32 + lg * 8);
#pragma unroll
    for (int nt = 0; nt < 4; ++nt) {
      bf16x8 bfr = *(const bf16x8*)(Wop + (size_t)(nt * 16 + lr) * 1024 + kk * 32 + lg * 8);
      acc[nt] = MFMA16(af, bfr, acc[nt]);
    }
  }
  if (kh == 1) {
#pragma unroll
    for (int nt = 0; nt < 4; ++nt)
#pragma unroll
      for (int j = 0; j < 4; ++j) red[wm][lg * 4 + j][nt * 16 + lr] = acc[nt][j];
  }
  __syncthreads();
  if (kh == 0) {
#pragma unroll
    for (int nt = 0; nt < 4; ++nt) {
      const int n = nt * 16 + lr;
      const float bb = bo[n];
#pragma unroll
      for (int j = 0; j < 4; ++j) {
        const int m = m0 + lg * 4 + j;
        float vv = acc[nt][j] + red[wm][lg * 4 + j][n] + bb;
        out[(size_t)m * 64 + n] = vv > 0.f ? vv : 0.f;
      }
    }
  }
}

// ---------------------------------------------------------------------------
extern "C" void kernel_launch(void* const* d_in, const int* in_sizes, int n_in,
                              void* d_out, int out_size, void* d_ws, size_t ws_size,
                              hipStream_t stream) {
  const float* x  = (const float*)d_in[0];
  const float* Wq = (const float*)d_in[1];
  const float* bq = (const float*)d_in[2];
  const float* Wk = (const float*)d_in[3];
  const float* bk = (const float*)d_in[4];
  const float* Wv = (const float*)d_in[5];
  const float* bv = (const float*)d_in[6];
  const float* Wo = (const float*)d_in[7];
  const float* bo = (const float*)d_in[8];
  float* out = (float*)d_out;            // z_out: 8*1024*64 = 524288 f32
  float* att = out + 524288;             // att:   8*16*1024*1024 f32

  // workspace layout (~92 MB)
  char* ws = (char*)d_ws;
  size_t off = 0;
  ushort* xb  = (ushort*)(ws + off); off += (size_t)8192 * 1024 * 2;
  ushort* Wp  = (ushort*)(ws + off); off += (size_t)3072 * 1024 * 2;
  ushort* Wop = (ushort*)(ws + off); off += (size_t)64 * 1024 * 2;
  float* bqkv = (float*)(ws + off);  off += (size_t)3072 * 4;
  ushort* q   = (ushort*)(ws + off); off += (size_t)128 * 1024 * 64 * 2;
  ushort* k   = (ushort*)(ws + off); off += (size_t)128 * 1024 * 64 * 2;
  ushort* vT  = (ushort*)(ws + off); off += (size_t)128 * 64 * 1024 * 2;
  ushort* hds = (ushort*)(ws + off); off += (size_t)8192 * 1024 * 2;
  (void)ws_size; (void)in_sizes; (void)n_in; (void)out_size;

  pack_x<<<dim3(8192), dim3(256), 0, stream>>>(x, xb);
  pack_w<<<dim3(12288), dim3(256), 0, stream>>>(Wq, Wk, Wv, Wp);
  pack_misc<<<dim3(269), dim3(256), 0, stream>>>(Wo, bq, bk, bv, Wop, bqkv);
  gemm_qkv<<<dim3(1536), dim3(256), 0, stream>>>(xb, Wp, bqkv, q, k, vT);
  attn_kernel<<<dim3(2048), dim3(256), 0, stream>>>(q, k, vT, att, hds);
  gemm_out<<<dim3(256), dim3(256), 0, stream>>>(hds, Wop, bo, out);
}